// Round 4
// baseline (73.871 us; speedup 1.0000x reference)
//
#include <hip/hip_runtime.h>
#include <math.h>

#define GG 2000   // num_graphs (reference constant)

typedef short bf16x8 __attribute__((ext_vector_type(8)));
typedef float f32x4  __attribute__((ext_vector_type(4)));

__device__ __forceinline__ unsigned short f2b(float f) {
    unsigned int u = __float_as_uint(f);
    u += 0x7FFFu + ((u >> 16) & 1u);          // round-to-nearest-even
    return (unsigned short)(u >> 16);
}

// seg[g] = first node index with batch[node] >= g, g in [0, GG]
__global__ void lbound_kernel(const int* __restrict__ batch, int* __restrict__ seg, int n) {
    int g = blockIdx.x * blockDim.x + threadIdx.x;
    if (g > GG) return;
    int lo = 0, hi = n;
    while (lo < hi) { int mid = (lo + hi) >> 1; if (batch[mid] < g) lo = mid + 1; else hi = mid; }
    seg[g] = lo;
}

// One block per graph. Flash-style: per 128-node window compute scores via MFMA
// (chunks of 64), then online softmax (rescale out accs across windows), then
// fp32 PV reading x from L1/L2 (rows just staged). x hits HBM exactly once.
__global__ __launch_bounds__(256, 2) void fused_kernel(
    const float* __restrict__ x, const float* __restrict__ w1,
    const float* __restrict__ w2, const int* __restrict__ seg,
    float* __restrict__ out)
{
    __shared__ __align__(16) unsigned short w1b[16384]; // [128 hid][128 k] bf16, slot^=(row&7)
    __shared__ __align__(16) unsigned short xb[8192];   // [64 node][128 k] bf16, swizzled
    __shared__ __align__(16) unsigned short hb[8192];   // [64 node][128 hid] bf16, swizzled
    __shared__ __align__(16) float sc[128 * 8];         // window scores -> attn (in-place)
    __shared__ float red[256];
    __shared__ float mstat[8], lstat[8], fac[8];

    const int t = threadIdx.x;
    const int lane = t & 63;
    const int w = t >> 6;
    const int l15 = lane & 15;
    const int lg = lane >> 4;

    // ---- stage w1 -> bf16 LDS once per block ----
#pragma unroll
    for (int i = 0; i < 16; ++i) {
        int f4 = i * 256 + t;                  // 4096 float4
        int row = f4 >> 5, q = f4 & 31;
        float4 v = ((const float4*)w1)[f4];
        ushort4 p;
        p.x = f2b(v.x); p.y = f2b(v.y); p.z = f2b(v.z); p.w = f2b(v.w);
        int slot = (q >> 1) ^ (row & 7);
        *(ushort4*)((char*)w1b + row * 256 + slot * 16 + (q & 1) * 8) = p;
    }
    // ---- w2 b-frags in regs: lane -> col o=l15 (rows 8..15 zero) ----
    bf16x8 w2f[4];
    {
        const int o = l15;
#pragma unroll
        for (int ks = 0; ks < 4; ++ks) {
            float tmp[8];
            if (o < 8) {
                float4 u0 = ((const float4*)w2)[o * 32 + ks * 8 + lg * 2];
                float4 u1 = ((const float4*)w2)[o * 32 + ks * 8 + lg * 2 + 1];
                tmp[0]=u0.x; tmp[1]=u0.y; tmp[2]=u0.z; tmp[3]=u0.w;
                tmp[4]=u1.x; tmp[5]=u1.y; tmp[6]=u1.z; tmp[7]=u1.w;
            } else {
#pragma unroll
                for (int i = 0; i < 8; ++i) tmp[i] = 0.f;
            }
            bf16x8 r;
#pragma unroll
            for (int i = 0; i < 8; ++i) r[i] = (short)f2b(tmp[i]);
            w2f[ks] = r;
        }
    }

    const int fcol = t & 127;
    const int ob = t >> 7;          // out accs cover o = ob*4 .. ob*4+3 at feature fcol
    const int o8 = t & 7;
    const int jj = t >> 3;

    for (int g = blockIdx.x; g < GG; g += gridDim.x) {
        const int s = seg[g];
        const int e = seg[g + 1];
        float a0 = 0.f, a1 = 0.f, a2 = 0.f, a3 = 0.f;
        __syncthreads();            // prev-graph epilogue reads done (also w1b on first iter)
        if (t < 8) { mstat[t] = -INFINITY; lstat[t] = 0.f; }

        for (int wstart = s; wstart < e; wstart += 128) {
            const int wcnt = min(128, e - wstart);
            // ---- pass 1: scores for window into sc ----
            for (int c = 0; c < wcnt; c += 64) {
                __syncthreads();    // xb free, prev-window PV done, stat init visible
                // stage x chunk -> bf16 LDS (coalesced: 32 lanes cover one row)
#pragma unroll
                for (int i = 0; i < 8; ++i) {
                    int row = i * 8 + (t >> 5);
                    int q = t & 31;
                    int node = wstart + c + row;
                    if (node >= e) node = e - 1;      // masked via -inf score later
                    float4 v = ((const float4*)x)[(size_t)node * 32 + q];
                    ushort4 p;
                    p.x = f2b(v.x); p.y = f2b(v.y); p.z = f2b(v.z); p.w = f2b(v.w);
                    int slot = (q >> 1) ^ (row & 7);
                    *(ushort4*)((char*)xb + row * 256 + slot * 16 + (q & 1) * 8) = p;
                }
                __syncthreads();
                // GEMM1: wave w -> chunk rows w*16..w*16+15
                f32x4 acc1[8];
#pragma unroll
                for (int nt = 0; nt < 8; ++nt)
#pragma unroll
                    for (int r = 0; r < 4; ++r) acc1[nt][r] = 0.f;
#pragma unroll
                for (int ks = 0; ks < 4; ++ks) {
                    int arow = w * 16 + l15;
                    int aslot = (ks * 4 + lg) ^ (arow & 7);
                    bf16x8 af = *(bf16x8*)((char*)xb + arow * 256 + aslot * 16);
#pragma unroll
                    for (int nt = 0; nt < 8; ++nt) {
                        int brow = nt * 16 + l15;
                        int bslot = (ks * 4 + lg) ^ (brow & 7);
                        bf16x8 bfr = *(bf16x8*)((char*)w1b + brow * 256 + bslot * 16);
                        acc1[nt] = __builtin_amdgcn_mfma_f32_16x16x32_bf16(af, bfr, acc1[nt], 0, 0, 0);
                    }
                }
                // tanh -> hb (wave-private rows; in-order LDS per wave => no barrier)
#pragma unroll
                for (int nt = 0; nt < 8; ++nt)
#pragma unroll
                    for (int r = 0; r < 4; ++r) {
                        float aa = acc1[nt][r];
                        float eo = __expf(-2.f * fabsf(aa));
                        float th = copysignf((1.f - eo) * __builtin_amdgcn_rcpf(1.f + eo), aa);
                        int m = w * 16 + lg * 4 + r;
                        int n = nt * 16 + l15;
                        int slot = (n >> 3) ^ (m & 7);
                        *(unsigned short*)((char*)hb + m * 256 + slot * 16 + (n & 7) * 2) = f2b(th);
                    }
                // GEMM2: scores for own rows
                f32x4 acc2;
#pragma unroll
                for (int r = 0; r < 4; ++r) acc2[r] = 0.f;
#pragma unroll
                for (int ks = 0; ks < 4; ++ks) {
                    int m = w * 16 + l15;
                    int slot = (ks * 4 + lg) ^ (m & 7);
                    bf16x8 hf = *(bf16x8*)((char*)hb + m * 256 + slot * 16);
                    acc2 = __builtin_amdgcn_mfma_f32_16x16x32_bf16(hf, w2f[ks], acc2, 0, 0, 0);
                }
                if (l15 < 8) {
#pragma unroll
                    for (int r = 0; r < 4; ++r) {
                        int row = c + w * 16 + lg * 4 + r;
                        sc[row * 8 + l15] = (row < wcnt) ? acc2[r] : -INFINITY;
                    }
                }
            }
            __syncthreads();        // sc complete
            // ---- window max per o ----
            float pm = -INFINITY;
            for (int j = jj; j < wcnt; j += 32) pm = fmaxf(pm, sc[j * 8 + o8]);
            red[t] = pm;
            __syncthreads();
            for (int st = 128; st >= 8; st >>= 1) { if (t < st) red[t] = fmaxf(red[t], red[t + st]); __syncthreads(); }
            if (t < 8) {
                float mo = mstat[t];
                float mn = fmaxf(mo, red[t]);
                fac[t] = __expf(mo - mn);   // first window: exp(-inf)=0, accs are 0
                mstat[t] = mn;
            }
            __syncthreads();
            // ---- exp in place + window sum ----
            {
                float mn = mstat[o8];
                float ps = 0.f;
                for (int j = jj; j < wcnt; j += 32) {
                    float v = __expf(sc[j * 8 + o8] - mn);
                    sc[j * 8 + o8] = v;
                    ps += v;
                }
                red[t] = ps;
            }
            __syncthreads();        // also orders sc exp-writes before PV reads
            for (int st = 128; st >= 8; st >>= 1) { if (t < st) red[t] += red[t + st]; __syncthreads(); }
            if (t < 8) lstat[t] = lstat[t] * fac[t] + red[t];
            // ---- rescale accs, then PV (x rows are L1/L2-hot from staging) ----
            a0 *= fac[ob * 4 + 0]; a1 *= fac[ob * 4 + 1]; a2 *= fac[ob * 4 + 2]; a3 *= fac[ob * 4 + 3];
            {
                const float* xg = x + (size_t)wstart * 128 + fcol;
                const float4* scv = (const float4*)sc;
                int j = 0;
                for (; j + 4 <= wcnt; j += 4) {
                    float x0 = xg[(j + 0) * 128];
                    float x1 = xg[(j + 1) * 128];
                    float x2 = xg[(j + 2) * 128];
                    float x3 = xg[(j + 3) * 128];
                    float4 p0 = scv[(j + 0) * 2 + ob];
                    float4 p1 = scv[(j + 1) * 2 + ob];
                    float4 p2 = scv[(j + 2) * 2 + ob];
                    float4 p3 = scv[(j + 3) * 2 + ob];
                    a0 = fmaf(p0.x, x0, a0); a1 = fmaf(p0.y, x0, a1); a2 = fmaf(p0.z, x0, a2); a3 = fmaf(p0.w, x0, a3);
                    a0 = fmaf(p1.x, x1, a0); a1 = fmaf(p1.y, x1, a1); a2 = fmaf(p1.z, x1, a2); a3 = fmaf(p1.w, x1, a3);
                    a0 = fmaf(p2.x, x2, a0); a1 = fmaf(p2.y, x2, a1); a2 = fmaf(p2.z, x2, a2); a3 = fmaf(p2.w, x2, a3);
                    a0 = fmaf(p3.x, x3, a0); a1 = fmaf(p3.y, x3, a1); a2 = fmaf(p3.z, x3, a2); a3 = fmaf(p3.w, x3, a3);
                }
                for (; j < wcnt; ++j) {
                    float xv = xg[j * 128];
                    float4 p = scv[j * 2 + ob];
                    a0 = fmaf(p.x, xv, a0); a1 = fmaf(p.y, xv, a1); a2 = fmaf(p.z, xv, a2); a3 = fmaf(p.w, xv, a3);
                }
            }
            // next window's barriers order sc/xb/red reuse
        }
        __syncthreads();            // lstat final, visible to all
        {
            float* og = out + (size_t)g * 1024 + ob * 512 + fcol;
            if (e > s) {
                og[0]   = a0 / lstat[ob * 4 + 0];
                og[128] = a1 / lstat[ob * 4 + 1];
                og[256] = a2 / lstat[ob * 4 + 2];
                og[384] = a3 / lstat[ob * 4 + 3];
            } else {
                og[0] = 0.f; og[128] = 0.f; og[256] = 0.f; og[384] = 0.f;  // empty graph
            }
        }
    }
}

extern "C" void kernel_launch(void* const* d_in, const int* in_sizes, int n_in,
                              void* d_out, int out_size, void* d_ws, size_t ws_size,
                              hipStream_t stream)
{
    const float* x     = (const float*)d_in[0];
    const int*   batch = (const int*)d_in[1];
    const float* w1    = (const float*)d_in[2];
    const float* w2    = (const float*)d_in[3];
    const int n_nodes  = in_sizes[1];
    float* out = (float*)d_out;

    int* seg = (int*)d_ws;   // GG+1 ints

    hipLaunchKernelGGL(lbound_kernel, dim3((GG + 256) / 256), dim3(256), 0, stream, batch, seg, n_nodes);
    hipLaunchKernelGGL(fused_kernel,  dim3(GG), dim3(256), 0, stream, x, w1, w2, seg, out);
}

// Round 5
// 67.479 us; speedup vs baseline: 1.0947x; 1.0947x over previous
//
#include <hip/hip_runtime.h>
#include <math.h>

#define GG 2000   // num_graphs (reference constant)

typedef short bf16x8 __attribute__((ext_vector_type(8)));
typedef float f32x4  __attribute__((ext_vector_type(4)));

__device__ __forceinline__ unsigned short f2b(float f) {
    unsigned int u = __float_as_uint(f);
    u += 0x7FFFu + ((u >> 16) & 1u);          // round-to-nearest-even
    return (unsigned short)(u >> 16);
}

// seg[g] = first node index with batch[node] >= g, g in [0, GG]
__global__ void lbound_kernel(const int* __restrict__ batch, int* __restrict__ seg, int n) {
    int g = blockIdx.x * blockDim.x + threadIdx.x;
    if (g > GG) return;
    int lo = 0, hi = n;
    while (lo < hi) { int mid = (lo + hi) >> 1; if (batch[mid] < g) lo = mid + 1; else hi = mid; }
    seg[g] = lo;
}

// Persistent fused kernel: grid=512 (2 blocks/CU resident), each block loops ~4 graphs.
// Per graph: flash windows of 128 (chunks of 64): stage x->bf16 LDS, GEMM1 (MFMA,
// w1 half in regs half in LDS), tanh, GEMM2 -> sc, barrier-lean online softmax,
// fp32 PV from L1/L2-hot global x.
__global__ __launch_bounds__(256, 2) void fused_kernel(
    const float* __restrict__ x, const float* __restrict__ w1,
    const float* __restrict__ w2, const int* __restrict__ seg,
    float* __restrict__ out)
{
    __shared__ __align__(16) unsigned short w1b[16384]; // [128 hid][128 k] bf16, slot^=(row&7)
    __shared__ __align__(16) unsigned short xb[8192];   // [64 node][128 k] bf16, swizzled
    __shared__ __align__(16) unsigned short hb[8192];   // [64 node][128 hid] bf16, swizzled
    __shared__ __align__(16) float sc[128 * 8];         // window scores -> attn (in-place)
    __shared__ float red[256];                          // max partials
    __shared__ float red2[256];                         // sum partials
    __shared__ float mstat[8], lstat[8], fac[8];

    const int t = threadIdx.x;
    const int lane = t & 63;
    const int w = t >> 6;
    const int l15 = lane & 15;
    const int lg = lane >> 4;

    // ---- stage w1 -> bf16 LDS once per block ----
#pragma unroll
    for (int i = 0; i < 16; ++i) {
        int f4 = i * 256 + t;                  // 4096 float4
        int row = f4 >> 5, q = f4 & 31;
        float4 v = ((const float4*)w1)[f4];
        ushort4 p;
        p.x = f2b(v.x); p.y = f2b(v.y); p.z = f2b(v.z); p.w = f2b(v.w);
        int slot = (q >> 1) ^ (row & 7);
        *(ushort4*)((char*)w1b + row * 256 + slot * 16 + (q & 1) * 8) = p;
    }
    // ---- w2 b-frags in regs: lane -> col o=l15 (rows 8..15 zero) ----
    bf16x8 w2f[4];
    {
        const int o = l15;
#pragma unroll
        for (int ks = 0; ks < 4; ++ks) {
            float tmp[8];
            if (o < 8) {
                float4 u0 = ((const float4*)w2)[o * 32 + ks * 8 + lg * 2];
                float4 u1 = ((const float4*)w2)[o * 32 + ks * 8 + lg * 2 + 1];
                tmp[0]=u0.x; tmp[1]=u0.y; tmp[2]=u0.z; tmp[3]=u0.w;
                tmp[4]=u1.x; tmp[5]=u1.y; tmp[6]=u1.z; tmp[7]=u1.w;
            } else {
#pragma unroll
                for (int i = 0; i < 8; ++i) tmp[i] = 0.f;
            }
            bf16x8 r;
#pragma unroll
            for (int i = 0; i < 8; ++i) r[i] = (short)f2b(tmp[i]);
            w2f[ks] = r;
        }
    }
    __syncthreads();   // w1b staged
    // ---- hoist w1 B-frags for nt=0..3 into registers (64 VGPR) ----
    bf16x8 bfreg[4][4];
#pragma unroll
    for (int ks = 0; ks < 4; ++ks)
#pragma unroll
        for (int nt = 0; nt < 4; ++nt) {
            int brow = nt * 16 + l15;
            int slot = (ks * 4 + lg) ^ (brow & 7);
            bfreg[ks][nt] = *(bf16x8*)((char*)w1b + brow * 256 + slot * 16);
        }

    const int fcol = t & 127;
    const int ob = t >> 7;          // out accs cover o = ob*4 .. ob*4+3 at feature fcol
    const int o8 = t & 7;
    const int jj = t >> 3;

    for (int g = blockIdx.x; g < GG; g += gridDim.x) {
        const int s = seg[g];
        const int e = seg[g + 1];
        float a0 = 0.f, a1 = 0.f, a2 = 0.f, a3 = 0.f;
        __syncthreads();            // prev-graph epilogue reads done
        if (t < 8) { mstat[t] = -INFINITY; lstat[t] = 0.f; }

        for (int wstart = s; wstart < e; wstart += 128) {
            const int wcnt = min(128, e - wstart);
            // ---- pass 1: scores for window into sc ----
            for (int c = 0; c < wcnt; c += 64) {
                if (c) __syncthreads();     // xb reuse within window
                // stage x chunk -> bf16 LDS (coalesced: 32 lanes cover one row)
#pragma unroll
                for (int i = 0; i < 8; ++i) {
                    int row = i * 8 + (t >> 5);
                    int q = t & 31;
                    int node = wstart + c + row;
                    if (node >= e) node = e - 1;
                    float4 v = ((const float4*)x)[(size_t)node * 32 + q];
                    ushort4 p;
                    p.x = f2b(v.x); p.y = f2b(v.y); p.z = f2b(v.z); p.w = f2b(v.w);
                    int slot = (q >> 1) ^ (row & 7);
                    *(ushort4*)((char*)xb + row * 256 + slot * 16 + (q & 1) * 8) = p;
                }
                __syncthreads();
                // GEMM1: wave w -> chunk rows w*16..w*16+15
                f32x4 acc1[8];
#pragma unroll
                for (int nt = 0; nt < 8; ++nt)
#pragma unroll
                    for (int r = 0; r < 4; ++r) acc1[nt][r] = 0.f;
#pragma unroll
                for (int ks = 0; ks < 4; ++ks) {
                    int arow = w * 16 + l15;
                    int aslot = (ks * 4 + lg) ^ (arow & 7);
                    bf16x8 af = *(bf16x8*)((char*)xb + arow * 256 + aslot * 16);
#pragma unroll
                    for (int nt = 0; nt < 4; ++nt)
                        acc1[nt] = __builtin_amdgcn_mfma_f32_16x16x32_bf16(af, bfreg[ks][nt], acc1[nt], 0, 0, 0);
#pragma unroll
                    for (int nt = 4; nt < 8; ++nt) {
                        int brow = nt * 16 + l15;
                        int bslot = (ks * 4 + lg) ^ (brow & 7);
                        bf16x8 bfr = *(bf16x8*)((char*)w1b + brow * 256 + bslot * 16);
                        acc1[nt] = __builtin_amdgcn_mfma_f32_16x16x32_bf16(af, bfr, acc1[nt], 0, 0, 0);
                    }
                }
                // tanh -> hb (wave-private rows; in-order LDS per wave => no barrier)
#pragma unroll
                for (int nt = 0; nt < 8; ++nt)
#pragma unroll
                    for (int r = 0; r < 4; ++r) {
                        float aa = acc1[nt][r];
                        float eo = __expf(-2.f * fabsf(aa));
                        float th = copysignf((1.f - eo) * __builtin_amdgcn_rcpf(1.f + eo), aa);
                        int m = w * 16 + lg * 4 + r;
                        int n = nt * 16 + l15;
                        int slot = (n >> 3) ^ (m & 7);
                        *(unsigned short*)((char*)hb + m * 256 + slot * 16 + (n & 7) * 2) = f2b(th);
                    }
                // GEMM2: scores for own rows
                f32x4 acc2;
#pragma unroll
                for (int r = 0; r < 4; ++r) acc2[r] = 0.f;
#pragma unroll
                for (int ks = 0; ks < 4; ++ks) {
                    int m = w * 16 + l15;
                    int slot = (ks * 4 + lg) ^ (m & 7);
                    bf16x8 hf = *(bf16x8*)((char*)hb + m * 256 + slot * 16);
                    acc2 = __builtin_amdgcn_mfma_f32_16x16x32_bf16(hf, w2f[ks], acc2, 0, 0, 0);
                }
                if (l15 < 8) {
#pragma unroll
                    for (int r = 0; r < 4; ++r) {
                        int row = c + w * 16 + lg * 4 + r;
                        if (row < wcnt) sc[row * 8 + l15] = acc2[r];
                    }
                }
            }
            __syncthreads();        // sc complete
            // ---- window max: partials -> red, one barrier, all-wave shuffle reduce ----
            float pm = -INFINITY;
            for (int j = jj; j < wcnt; j += 32) pm = fmaxf(pm, sc[j * 8 + o8]);
            red[t] = pm;
            __syncthreads();
            float v = fmaxf(fmaxf(red[lane], red[lane + 64]), fmaxf(red[lane + 128], red[lane + 192]));
            v = fmaxf(v, __shfl_xor(v, 8));
            v = fmaxf(v, __shfl_xor(v, 16));
            v = fmaxf(v, __shfl_xor(v, 32));     // v = window-max for o = lane&7 (== o8)
            float mo = mstat[o8];                // racy vs wave0 write but fmax-idempotent
            float mn = fmaxf(mo, v);
            if (w == 0 && lane < 8) { fac[lane] = __expf(mo - mn); mstat[lane] = mn; }
            // ---- exp in place (reg mn) + sum partials -> red2 ----
            float ps = 0.f;
            for (int j = jj; j < wcnt; j += 32) {
                float vv = __expf(sc[j * 8 + o8] - mn);
                sc[j * 8 + o8] = vv;
                ps += vv;
            }
            red2[t] = ps;
            __syncthreads();        // sc exp'd + red2 + fac/mstat all visible
            if (w == 0) {
                float sv = (red2[lane] + red2[lane + 64]) + (red2[lane + 128] + red2[lane + 192]);
                sv += __shfl_xor(sv, 8);
                sv += __shfl_xor(sv, 16);
                sv += __shfl_xor(sv, 32);
                if (lane < 8) lstat[lane] = lstat[lane] * fac[lane] + sv;  // consumed at epilogue
            }
            // ---- rescale accs, then PV (x rows L1/L2-hot from staging) ----
            a0 *= fac[ob * 4 + 0]; a1 *= fac[ob * 4 + 1]; a2 *= fac[ob * 4 + 2]; a3 *= fac[ob * 4 + 3];
            {
                const float* xg = x + (size_t)wstart * 128 + fcol;
                const float4* scv = (const float4*)sc;
                int j = 0;
                for (; j + 4 <= wcnt; j += 4) {
                    float x0 = xg[(j + 0) * 128];
                    float x1 = xg[(j + 1) * 128];
                    float x2 = xg[(j + 2) * 128];
                    float x3 = xg[(j + 3) * 128];
                    float4 p0 = scv[(j + 0) * 2 + ob];
                    float4 p1 = scv[(j + 1) * 2 + ob];
                    float4 p2 = scv[(j + 2) * 2 + ob];
                    float4 p3 = scv[(j + 3) * 2 + ob];
                    a0 = fmaf(p0.x, x0, a0); a1 = fmaf(p0.y, x0, a1); a2 = fmaf(p0.z, x0, a2); a3 = fmaf(p0.w, x0, a3);
                    a0 = fmaf(p1.x, x1, a0); a1 = fmaf(p1.y, x1, a1); a2 = fmaf(p1.z, x1, a2); a3 = fmaf(p1.w, x1, a3);
                    a0 = fmaf(p2.x, x2, a0); a1 = fmaf(p2.y, x2, a1); a2 = fmaf(p2.z, x2, a2); a3 = fmaf(p2.w, x2, a3);
                    a0 = fmaf(p3.x, x3, a0); a1 = fmaf(p3.y, x3, a1); a2 = fmaf(p3.z, x3, a2); a3 = fmaf(p3.w, x3, a3);
                }
                for (; j < wcnt; ++j) {
                    float xv = xg[j * 128];
                    float4 p = scv[j * 2 + ob];
                    a0 = fmaf(p.x, xv, a0); a1 = fmaf(p.y, xv, a1); a2 = fmaf(p.z, xv, a2); a3 = fmaf(p.w, xv, a3);
                }
            }
        }
        __syncthreads();            // lstat final, visible to all
        {
            float* og = out + (size_t)g * 1024 + ob * 512 + fcol;
            if (e > s) {
                og[0]   = a0 / lstat[ob * 4 + 0];
                og[128] = a1 / lstat[ob * 4 + 1];
                og[256] = a2 / lstat[ob * 4 + 2];
                og[384] = a3 / lstat[ob * 4 + 3];
            } else {
                og[0] = 0.f; og[128] = 0.f; og[256] = 0.f; og[384] = 0.f;  // empty graph
            }
        }
    }
}

extern "C" void kernel_launch(void* const* d_in, const int* in_sizes, int n_in,
                              void* d_out, int out_size, void* d_ws, size_t ws_size,
                              hipStream_t stream)
{
    const float* x     = (const float*)d_in[0];
    const int*   batch = (const int*)d_in[1];
    const float* w1    = (const float*)d_in[2];
    const float* w2    = (const float*)d_in[3];
    const int n_nodes  = in_sizes[1];
    float* out = (float*)d_out;

    int* seg = (int*)d_ws;   // GG+1 ints

    hipLaunchKernelGGL(lbound_kernel, dim3((GG + 256) / 256), dim3(256), 0, stream, batch, seg, n_nodes);
    hipLaunchKernelGGL(fused_kernel,  dim3(512), dim3(256), 0, stream, x, w1, w2, seg, out);
}